// Round 4
// baseline (4217.036 us; speedup 1.0000x reference)
//
#include <hip/hip_runtime.h>
#include <hip/hip_bf16.h>

#define B_DIM 16
#define S_DIM 4096
#define N_DIM 256
#define EPS 1e-5f

typedef float f2 __attribute__((ext_vector_type(2)));

// Packed dual-FMA on the f32 vector pipe; "v" constraints force arch VGPRs.
__device__ __forceinline__ void pk_fma(f2& d, f2 a, f2 b) {
    asm("v_pk_fma_f32 %0, %1, %2, %0" : "+v"(d) : "v"(a), "v"(b));
}

// Workgroup barrier that only drains LDS (lgkmcnt), NOT vmcnt: keeps the Bu
// prefetch loads and y stores in flight across steps. All cross-thread data
// in the scan flows through LDS, so this is sufficient ordering.
__device__ __forceinline__ void bar_lds() {
    asm volatile("s_waitcnt lgkmcnt(0)\n\ts_barrier" ::: "memory");
}

// x[lane] + x[lane^32] in every lane. VALU-pipe permlane32_swap on gfx950
// (either swap direction gives the same sum since both inputs equal x);
// DS-pipe shuffle fallback otherwise.
__device__ __forceinline__ float pairsum32(float x) {
#if __has_builtin(__builtin_amdgcn_permlane32_swap)
    auto r = __builtin_amdgcn_permlane32_swap(__float_as_uint(x),
                                              __float_as_uint(x), false, false);
    union { decltype(r) v; unsigned u[2]; } cv;
    cv.v = r;
    return __uint_as_float(cv.u[0]) + __uint_as_float(cv.u[1]);
#else
    return x + __shfl_xor(x, 32, 64);
#endif
}

// DPP helper for the wave64 reduction (VALU pipe).
template<int CTRL>
__device__ __forceinline__ float dpp_term(float x) {
    return __int_as_float(
        __builtin_amdgcn_update_dpp(0, __float_as_int(x), CTRL, 0xF, 0xF, true));
}

// Full-wave (64-lane) sum; result valid in lane 63.
__device__ __forceinline__ float wave_sum_l63(float v) {
    v += dpp_term<0x111>(v);   // row_shr:1
    v += dpp_term<0x112>(v);   // row_shr:2
    v += dpp_term<0x114>(v);   // row_shr:4
    v += dpp_term<0x118>(v);   // row_shr:8
    v += dpp_term<0x142>(v);   // row_bcast:15
    v += dpp_term<0x143>(v);   // row_bcast:31
    return v;
}

// ---------------------------------------------------------------------------
// Tiled f32 GEMM: Y[M,256] = X[M,256] @ W[256,256]^T + bias
// ---------------------------------------------------------------------------
__global__ __launch_bounds__(256)
void gemm_xwT_bias(const float* __restrict__ X,
                   const float* __restrict__ W,
                   const float* __restrict__ bias,
                   float* __restrict__ Y,
                   int M)
{
    __shared__ float Xs[16][68];
    __shared__ float Ws[16][68];

    const int tid = threadIdx.x;
    const int m0 = blockIdx.x * 64;
    const int n0 = blockIdx.y * 64;
    const int tx = tid & 15;
    const int ty = tid >> 4;

    float acc[4][4] = {};

    for (int k0 = 0; k0 < 256; k0 += 16) {
        {
            const int r  = tid >> 2;
            const int kk = (tid & 3) * 4;
            float4 v = *(const float4*)(X + (size_t)(m0 + r) * 256 + k0 + kk);
            Xs[kk + 0][r] = v.x; Xs[kk + 1][r] = v.y;
            Xs[kk + 2][r] = v.z; Xs[kk + 3][r] = v.w;
            float4 w = *(const float4*)(W + (size_t)(n0 + r) * 256 + k0 + kk);
            Ws[kk + 0][r] = w.x; Ws[kk + 1][r] = w.y;
            Ws[kk + 2][r] = w.z; Ws[kk + 3][r] = w.w;
        }
        __syncthreads();

        #pragma unroll
        for (int k = 0; k < 16; ++k) {
            float4 xv = *(const float4*)&Xs[k][ty * 4];
            float4 wv = *(const float4*)&Ws[k][tx * 4];
            float xa[4] = {xv.x, xv.y, xv.z, xv.w};
            float wa[4] = {wv.x, wv.y, wv.z, wv.w};
            #pragma unroll
            for (int i = 0; i < 4; ++i)
                #pragma unroll
                for (int j = 0; j < 4; ++j)
                    acc[i][j] += xa[i] * wa[j];
        }
        __syncthreads();
    }

    const int nbase = n0 + tx * 4;
    float4 bv = *(const float4*)(bias + nbase);
    #pragma unroll
    for (int i = 0; i < 4; ++i) {
        const int m = m0 + ty * 4 + i;
        float4 o;
        o.x = acc[i][0] + bv.x;
        o.y = acc[i][1] + bv.y;
        o.z = acc[i][2] + bv.z;
        o.w = acc[i][3] + bv.w;
        *(float4*)(Y + (size_t)m * 256 + nbase) = o;
    }
}

// ---------------------------------------------------------------------------
// Sequential scan, v4: 512 threads (8 waves) per batch.
// Thread t: og = t&31, kg = t>>5 (0..15). A rows {32r+og, r<8} x cols
// [16kg,16kg+16) held as f2 a2[8][8] (128 VGPRs, pk_fma-constrained).
// Wave w covers kg = {2w, 2w+1}; after the FMA block, permlane32_swap
// combines the two halves so only 8 K-groups of partials hit LDS:
//   s_partial[kg2*384 + og*12 + q*4 + i]  (q = r>>2, i = r&3; 12-stride pad)
// ph2: owners (t<256) read 8 partials + Bu, DPP LN stats.
// ph3: owners normalize, ReLU, write state to LDS + global.
// All barriers are lgkm-only so Bu prefetch / y stores stay in flight.
// ---------------------------------------------------------------------------
__global__ __launch_bounds__(512, 2)
void scan_kernel(const float* __restrict__ A,     // [256,256]
                 const float* __restrict__ Bu,    // [16,4096,256]
                 const float* __restrict__ ln_g,
                 const float* __restrict__ ln_b,
                 float* __restrict__ states)      // [16,4096,256]
{
    const int b    = blockIdx.x;
    const int t    = threadIdx.x;
    const int lane = t & 63;
    const int w    = t >> 6;      // wave 0..7 (== kg2 for this wave's pair)
    const int og   = t & 31;
    const int kg   = t >> 5;      // 0..15, uniform per half-wave

    __shared__ float s_state[256];
    __shared__ float s_partial[8 * 384];          // 12 KB, padded stride 12
    __shared__ __align__(16) float s_red[8];      // [0..3]=sums, [4..7]=sumsqs

    // --- A fragment -> 64 f2 (128 VGPRs)
    f2 a2[8][8];
    #pragma unroll
    for (int r = 0; r < 8; ++r) {
        const float* arow = A + (size_t)(32 * r + og) * 256 + kg * 16;
        #pragma unroll
        for (int c4 = 0; c4 < 4; ++c4) {
            float4 v = ((const float4*)arow)[c4];
            a2[r][2 * c4 + 0] = f2{v.x, v.y};
            a2[r][2 * c4 + 1] = f2{v.z, v.w};
        }
    }

    const bool owner = (t < 256);
    float g = 0.0f, beta = 0.0f;
    if (owner) { g = ln_g[t]; beta = ln_b[t]; }
    if (owner) s_state[t] = 0.0f;

    const float* bu_base  = Bu + (size_t)b * S_DIM * N_DIM;
    float*       out_base = states + (size_t)b * S_DIM * N_DIM;

    float bu0 = 0.0f, bu1 = 0.0f;
    if (owner) {
        bu0 = bu_base[t];
        bu1 = bu_base[N_DIM + t];
    }

    // owner read base for the 8 combined partials
    const int rd_base = og * 12 + ((t >> 7) << 2) + ((t >> 5) & 3);

    bar_lds();

    for (int step = 0; step < S_DIM; ++step) {
        // prefetch Bu for step+2 (stays in flight across lgkm-only barriers)
        float bu2 = 0.0f;
        if (owner && step + 2 < S_DIM)
            bu2 = bu_base[(size_t)(step + 2) * N_DIM + t];

        // --- ph1: packed partial matvec over this thread's 16-col slice ---
        const float4* sp = (const float4*)(s_state + kg * 16);
        f2 s2[8];
        #pragma unroll
        for (int c4 = 0; c4 < 4; ++c4) {
            float4 sv = sp[c4];
            s2[2 * c4 + 0] = f2{sv.x, sv.y};
            s2[2 * c4 + 1] = f2{sv.z, sv.w};
        }
        float p[8];
        #pragma unroll
        for (int r = 0; r < 8; ++r) {
            f2 acc2 = f2{0.0f, 0.0f};
            #pragma unroll
            for (int j = 0; j < 8; ++j)
                pk_fma(acc2, a2[r][j], s2[j]);
            p[r] = acc2.x + acc2.y;
        }
        // combine the wave's two K-groups (kg=2w,2w+1) in-register
        #pragma unroll
        for (int r = 0; r < 8; ++r)
            p[r] = pairsum32(p[r]);
        if (lane < 32) {
            float* dst = &s_partial[w * 384 + og * 12];
            *(float4*)(dst + 0) = make_float4(p[0], p[1], p[2], p[3]);
            *(float4*)(dst + 4) = make_float4(p[4], p[5], p[6], p[7]);
        }
        bar_lds();

        // --- ph2: owners reduce 8 combined partials, add Bu, DPP LN stats ---
        float v = 0.0f;
        if (owner) {
            float x0 = s_partial[0 * 384 + rd_base];
            float x1 = s_partial[1 * 384 + rd_base];
            float x2 = s_partial[2 * 384 + rd_base];
            float x3 = s_partial[3 * 384 + rd_base];
            float x4 = s_partial[4 * 384 + rd_base];
            float x5 = s_partial[5 * 384 + rd_base];
            float x6 = s_partial[6 * 384 + rd_base];
            float x7 = s_partial[7 * 384 + rd_base];
            v = (((x0 + x1) + (x2 + x3)) + ((x4 + x5) + (x6 + x7))) + bu0;

            float sum   = wave_sum_l63(v);
            float sumsq = wave_sum_l63(v * v);
            if (lane == 63) { s_red[w] = sum; s_red[4 + w] = sumsq; }
        }
        bar_lds();

        // --- ph3: owners normalize, ReLU, write state ---
        if (owner) {
            float4 sA = *(const float4*)&s_red[0];
            float4 sB = *(const float4*)&s_red[4];
            const float tot  = (sA.x + sA.y) + (sA.z + sA.w);
            const float tot2 = (sB.x + sB.y) + (sB.z + sB.w);
            const float mu  = tot * (1.0f / 256.0f);
            const float var = tot2 * (1.0f / 256.0f) - mu * mu;
            const float inv = rsqrtf(var + EPS);
            float y = (v - mu) * inv * g + beta;
            y = fmaxf(y, 0.0f);
            s_state[t] = y;
            out_base[(size_t)step * N_DIM + t] = y;
            bu0 = bu1;
            bu1 = bu2;
        }
        bar_lds();
    }
}

// ---------------------------------------------------------------------------
extern "C" void kernel_launch(void* const* d_in, const int* in_sizes, int n_in,
                              void* d_out, int out_size, void* d_ws, size_t ws_size,
                              hipStream_t stream)
{
    const float* u    = (const float*)d_in[0];
    const float* A    = (const float*)d_in[1];
    const float* B_w  = (const float*)d_in[2];
    const float* B_b  = (const float*)d_in[3];
    const float* ln_g = (const float*)d_in[4];
    const float* ln_b = (const float*)d_in[5];
    const float* C_w  = (const float*)d_in[6];
    const float* C_b  = (const float*)d_in[7];

    float* states  = (float*)d_out;
    float* outputs = (float*)d_out + (size_t)B_DIM * S_DIM * N_DIM;

    // Stage Bu in the outputs region (dead until kernel 3 overwrites it).
    float* Bu = outputs;

    const int M = B_DIM * S_DIM;   // 65536

    // 1) Bu = u @ B_w^T + B_b
    {
        dim3 grid(M / 64, N_DIM / 64);
        hipLaunchKernelGGL(gemm_xwT_bias, grid, dim3(256), 0, stream,
                           u, B_w, B_b, Bu, M);
    }

    // 2) sequential scan -> states
    {
        hipLaunchKernelGGL(scan_kernel, dim3(B_DIM), dim3(512), 0, stream,
                           A, Bu, ln_g, ln_b, states);
    }

    // 3) outputs = states @ C_w^T + C_b
    {
        dim3 grid(M / 64, N_DIM / 64);
        hipLaunchKernelGGL(gemm_xwT_bias, grid, dim3(256), 0, stream,
                           states, C_w, C_b, outputs, M);
    }
}